// Round 1
// baseline (1088.206 us; speedup 1.0000x reference)
//
#include <hip/hip_runtime.h>
#include <cstdint>
#include <cstddef>

#define C_    128
#define T_    300
#define V_    25
#define KA    3
#define TT    2
#define WPAD  32
#define NPOS  (TT*WPAD)     // 64
#define KDIM  384           // KA*C_
#define B2P   392           // padded LDS pitch (16B-aligned, 2-way banks)
#define ALP   40            // Albf v-pitch (16B-aligned, 2-way banks)
#define NSLOT 256
#define NTOT  64

typedef __attribute__((ext_vector_type(8))) short short8;
typedef __attribute__((ext_vector_type(4))) short short4v;
typedef __attribute__((ext_vector_type(4))) float float4v;

__device__ __forceinline__ short f2bf(float f) {
  union { float f; uint32_t u; } v; v.f = f;
  uint32_t r = (v.u + 0x7FFFu + ((v.u >> 16) & 1u)) >> 16;
  return (short)(uint16_t)r;
}

// ---------------- K0: precompute W2 (bf16, [c][k*128+c']), bias2, zero stats
__global__ __launch_bounds__(256) void k0_prep(const float* __restrict__ W,
    const float* __restrict__ A, const float* __restrict__ b,
    short* __restrict__ W2, float* __restrict__ bias2, float* __restrict__ stats)
{
  int e = blockIdx.x * 256 + threadIdx.x;
  if (e < C_*KDIM) {                         // 49152: W2[c][kd] = W[k*128+c][c']
    int c = e / KDIM, kd = e % KDIM;
    int k = kd >> 7, c2 = kd & 127;
    W2[e] = f2bf(W[(k*C_ + c)*C_ + c2]);
  } else if (e < C_*KDIM + C_*32) {          // bias2[c][w] = sum_k b[kC+c]*colsumA[k][w]
    int i = e - C_*KDIM;
    int c = i >> 5, w = i & 31;
    float val = 0.f;
    if (w < V_) {
      for (int k = 0; k < KA; ++k) {
        float cs = 0.f;
        for (int v = 0; v < V_; ++v) cs += A[(k*V_ + v)*V_ + w];
        val += b[k*C_ + c] * cs;
      }
    }
    bias2[i] = val;
  } else if (e < C_*KDIM + C_*32 + 2*NSLOT*C_) {  // zero 65536 stat floats
    stats[e - (C_*KDIM + C_*32)] = 0.f;
  }
}

// ---------------- K1: fused agg-MFMA -> conv-MFMA -> residual+relu -> Z + BN partials
__global__ __launch_bounds__(256) void k1_main(const float* __restrict__ x,
    const float* __restrict__ A, const short* __restrict__ W2,
    const float* __restrict__ bias2, float* __restrict__ ssum,
    float* __restrict__ ssq, float* __restrict__ out)
{
  __shared__ short Albf[KA][WPAD][ALP];   // A^T: [k][w][v], zero-padded
  __shared__ short B2[NPOS][B2P];         // X': [pos=t*32+w][kd=k*128+c']

  const int tid  = threadIdx.x;
  const int lane = tid & 63;
  const int wid  = tid >> 6;
  const int l15  = lane & 15;
  const int quad = lane >> 4;
  const int nb = blockIdx.x;
  const int n  = nb / (T_/TT);
  const int tb = nb % (T_/TT);
  const int t0 = tb * TT;

  for (int i = tid; i < KA*WPAD*ALP; i += 256) {
    int k = i / (WPAD*ALP);
    int rem = i % (WPAD*ALP);
    int w = rem / ALP;
    int v = rem % ALP;
    float a = (w < V_ && v < V_) ? A[(k*V_ + v)*V_ + w] : 0.f;
    ((short*)Albf)[i] = f2bf(a);
  }
  __syncthreads();

  // ---- stage 1: X'[k*128+c'][t*32+w] = sum_v x[c',t,v]*A[k,v,w]  (12 units / 4 waves)
  #pragma unroll
  for (int iu = 0; iu < 3; ++iu) {
    int u  = wid*3 + iu;
    int mh = u / 6;          // c'-half
    int k  = (u >> 1) % 3;
    int t  = u & 1;
    short8 bf0 = *(const short8*)&Albf[k][l15][quad*8];
    short8 bf1 = *(const short8*)&Albf[k][16 + l15][quad*8];
    #pragma unroll
    for (int mi4 = 0; mi4 < 4; ++mi4) {
      int mi = mh*4 + mi4;
      int cp = mi*16 + l15;
      const float* xr = x + (((size_t)n*C_ + cp)*T_ + (t0 + t))*V_;
      short8 af;
      int v0 = quad*8;
      #pragma unroll
      for (int j = 0; j < 8; ++j) {
        int v = v0 + j;
        af[j] = (v < V_) ? f2bf(xr[v]) : (short)0;
      }
      int c2 = k*C_ + mi*16 + quad*4;   // kd base for this lane's 4 output rows
      #pragma unroll
      for (int ni = 0; ni < 2; ++ni) {
        float4v acc = {0.f, 0.f, 0.f, 0.f};
        acc = __builtin_amdgcn_mfma_f32_16x16x32_bf16(af, ni ? bf1 : bf0, acc, 0, 0, 0);
        short4v sv;
        sv[0] = f2bf(acc[0]); sv[1] = f2bf(acc[1]);
        sv[2] = f2bf(acc[2]); sv[3] = f2bf(acc[3]);
        int pos = t*WPAD + ni*16 + l15;
        *(short4v*)&B2[pos][c2] = sv;
      }
    }
  }
  __syncthreads();

  // ---- stage 2: Z[c][pos] = sum_kd W2[c][kd] * X'[kd][pos]
  const int wm = wid >> 1;   // c-half
  const int wn = wid & 1;    // pos-half (== t since NPOS=64)
  float4v acc[4][2];
  #pragma unroll
  for (int mi = 0; mi < 4; ++mi)
    #pragma unroll
    for (int ni = 0; ni < 2; ++ni)
      acc[mi][ni] = (float4v){0.f, 0.f, 0.f, 0.f};

  #pragma unroll 4
  for (int ks = 0; ks < 12; ++ks) {
    short8 bfr0 = *(const short8*)&B2[wn*32 + l15][ks*32 + quad*8];
    short8 bfr1 = *(const short8*)&B2[wn*32 + 16 + l15][ks*32 + quad*8];
    #pragma unroll
    for (int mi = 0; mi < 4; ++mi) {
      int c = wm*64 + mi*16 + l15;
      short8 afr = *(const short8*)(W2 + (size_t)c*KDIM + ks*32 + quad*8);
      acc[mi][0] = __builtin_amdgcn_mfma_f32_16x16x32_bf16(afr, bfr0, acc[mi][0], 0, 0, 0);
      acc[mi][1] = __builtin_amdgcn_mfma_f32_16x16x32_bf16(afr, bfr1, acc[mi][1], 0, 0, 0);
    }
  }

  // ---- epilogue: +bias2 +x residual, relu, store Z, BN partial sums
  float lsum[4][4], lsq[4][4];
  #pragma unroll
  for (int a1 = 0; a1 < 4; ++a1)
    #pragma unroll
    for (int a2 = 0; a2 < 4; ++a2) { lsum[a1][a2] = 0.f; lsq[a1][a2] = 0.f; }

  #pragma unroll
  for (int ni = 0; ni < 2; ++ni) {
    int pos = wn*32 + ni*16 + l15;
    int t = pos >> 5;
    int w = pos & 31;
    if (w < V_) {
      #pragma unroll
      for (int mi = 0; mi < 4; ++mi) {
        int cb = wm*64 + mi*16 + quad*4;
        #pragma unroll
        for (int r = 0; r < 4; ++r) {
          int cc = cb + r;
          float z = acc[mi][ni][r] + bias2[cc*32 + w];
          size_t xi = (((size_t)n*C_ + cc)*T_ + (t0 + t))*V_ + w;
          z += x[xi];
          z = fmaxf(z, 0.f);
          out[xi] = z;
          lsum[mi][r] += z;
          lsq[mi][r]  += z*z;
        }
      }
    }
  }

  int slot = nb & (NSLOT - 1);
  #pragma unroll
  for (int mi = 0; mi < 4; ++mi) {
    #pragma unroll
    for (int r = 0; r < 4; ++r) {
      float s = lsum[mi][r];
      float q = lsq[mi][r];
      #pragma unroll
      for (int m = 1; m <= 8; m <<= 1) {
        s += __shfl_xor(s, m, 64);
        q += __shfl_xor(q, m, 64);
      }
      if (l15 == 0) {
        int cc = wm*64 + mi*16 + quad*4 + r;
        atomicAdd(&ssum[slot*C_ + cc], s);
        atomicAdd(&ssq[slot*C_ + cc], q);
      }
    }
  }
}

// ---------------- K2: finalize BN scale/shift; copy A to output tail
__global__ __launch_bounds__(256) void k2_stats(const float* __restrict__ ssum,
    const float* __restrict__ ssq, const float* __restrict__ gamma,
    const float* __restrict__ beta, const float* __restrict__ A,
    float* __restrict__ sscale, float* __restrict__ sshift, float* __restrict__ outA)
{
  int id = blockIdx.x * 256 + threadIdx.x;
  if (id < C_) {
    float s = 0.f, q = 0.f;
    for (int sl = 0; sl < NSLOT; ++sl) { s += ssum[sl*C_ + id]; q += ssq[sl*C_ + id]; }
    const float cnt = 480000.f;   // N*T*V
    float mean = s / cnt;
    float var  = q / cnt - mean*mean;
    float inv  = rsqrtf(var + 1e-5f);
    float sc   = gamma[id] * inv;
    sscale[id] = sc;
    sshift[id] = beta[id] - mean * sc;
  } else if (id < C_ + KA*V_*V_) {
    int i = id - C_;
    outA[i] = A[i];
  }
}

// ---------------- K3: in-place normalize (float4)
__global__ __launch_bounds__(256) void k3_bn(float* __restrict__ out,
    const float* __restrict__ sscale, const float* __restrict__ sshift)
{
  uint32_t i = blockIdx.x * 256u + threadIdx.x;   // < 15,360,000 float4s
  float4v* p = (float4v*)out;
  float4v z = p[i];
  int c = (int)((i / 1875u) & 127u);  // 7500 floats per (n,c) slab, /4
  float sc = sscale[c], sh = sshift[c];
  z[0] = z[0]*sc + sh; z[1] = z[1]*sc + sh;
  z[2] = z[2]*sc + sh; z[3] = z[3]*sc + sh;
  p[i] = z;
}

extern "C" void kernel_launch(void* const* d_in, const int* in_sizes, int n_in,
                              void* d_out, int out_size, void* d_ws, size_t ws_size,
                              hipStream_t stream)
{
  const float* x     = (const float*)d_in[0];
  const float* A     = (const float*)d_in[1];
  const float* W     = (const float*)d_in[2];
  const float* b     = (const float*)d_in[3];
  const float* gamma = (const float*)d_in[4];
  const float* beta  = (const float*)d_in[5];
  float* out = (float*)d_out;

  // ws layout (377,856 B total):
  short* W2    = (short*)d_ws;                          // 98,304 B
  float* bias2 = (float*)((char*)d_ws + 98304);         // 16,384 B
  float* stats = (float*)((char*)d_ws + 114688);        // 262,144 B (sum|sq)
  float* ssum   = stats;
  float* ssq    = stats + NSLOT*C_;
  float* sscale = stats + 2*NSLOT*C_;                   // 512 B
  float* sshift = sscale + C_;                          // 512 B
  float* outA = out + (size_t)NTOT*C_*T_*V_;            // A tail at 61,440,000

  k0_prep <<<464,   256, 0, stream>>>(W, A, b, W2, bias2, stats);
  k1_main <<<9600,  256, 0, stream>>>(x, A, W2, bias2, ssum, ssq, out);
  k2_stats<<<8,     256, 0, stream>>>(ssum, ssq, gamma, beta, A, sscale, sshift, outA);
  k3_bn   <<<60000, 256, 0, stream>>>(out, sscale, sshift);
}

// Round 2
// 982.027 us; speedup vs baseline: 1.1081x; 1.1081x over previous
//
#include <hip/hip_runtime.h>
#include <cstdint>
#include <cstddef>

#define C_    128
#define T_    300
#define V_    25
#define TT    2
#define KA    3
#define WPAD  32
#define NPOS  64            // TT*WPAD
#define KDIM  384           // KA*C_
#define B2P   392           // B2 LDS pitch (16B-aligned, ~2-way banks)
#define ALP   40            // Albf v-pitch
#define XTP   40            // xt v-pitch (zero-padded v>=25)
#define NSLOT 64
#define NTOT  64

typedef __attribute__((ext_vector_type(8))) short short8;
typedef __attribute__((ext_vector_type(4))) short short4v;
typedef __attribute__((ext_vector_type(4))) float float4v;
typedef __attribute__((ext_vector_type(2))) float float2v;

__device__ __forceinline__ short f2bf(float f) {
  union { float f; uint32_t u; } v; v.f = f;
  uint32_t r = (v.u + 0x7FFFu + ((v.u >> 16) & 1u)) >> 16;
  return (short)(uint16_t)r;
}
__device__ __forceinline__ float bf2f(short s) {
  union { uint32_t u; float f; } v; v.u = ((uint32_t)(uint16_t)s) << 16;
  return v.f;
}

// ---------------- K0: precompute W2 (bf16, [c][k*128+c']), bias2, zero stats
__global__ __launch_bounds__(256) void k0_prep(const float* __restrict__ W,
    const float* __restrict__ A, const float* __restrict__ b,
    short* __restrict__ W2, float* __restrict__ bias2, float* __restrict__ stats)
{
  int e = blockIdx.x * 256 + threadIdx.x;
  if (e < C_*KDIM) {                         // W2[c][kd] = W[k*128+c][c']
    int c = e / KDIM, kd = e % KDIM;
    int k = kd >> 7, c2 = kd & 127;
    W2[e] = f2bf(W[(k*C_ + c)*C_ + c2]);
  } else if (e < C_*KDIM + C_*32) {          // bias2[c][w] = sum_k b[kC+c]*colsumA[k][w]
    int i = e - C_*KDIM;
    int c = i >> 5, w = i & 31;
    float val = 0.f;
    if (w < V_) {
      for (int k = 0; k < KA; ++k) {
        float cs = 0.f;
        for (int v = 0; v < V_; ++v) cs += A[(k*V_ + v)*V_ + w];
        val += b[k*C_ + c] * cs;
      }
    }
    bias2[i] = val;
  } else if (e < C_*KDIM + C_*32 + 2*NSLOT*C_) {  // zero stat floats
    stats[e - (C_*KDIM + C_*32)] = 0.f;
  }
}

// ---------------- K1: fused agg-MFMA -> conv-MFMA -> residual+relu -> out + BN partials
__global__ __launch_bounds__(256) void k1_main(const float* __restrict__ x,
    const float* __restrict__ A, const short* __restrict__ W2,
    const float* __restrict__ bias2, float* __restrict__ ssum,
    float* __restrict__ ssq, float* __restrict__ out)
{
  __shared__ short Albf[KA][WPAD][ALP];   // A^T: [k][w][v], zero-padded
  __shared__ short xt[TT][C_][XTP];       // bf16 x-tile [t][c'][v], zero-padded v>=25
  __shared__ short B2[NPOS][B2P];         // X': [pos=t*32+w][kd]; later aliased as Zs (fp32 [128][50])

  const int tid  = threadIdx.x;
  const int lane = tid & 63;
  const int wid  = tid >> 6;
  const int l15  = lane & 15;
  const int quad = lane >> 4;
  const int nb = blockIdx.x;
  const int n  = nb / (T_/TT);
  const int tb = nb % (T_/TT);
  const int t0 = tb * TT;

  // Albf fill
  for (int i = tid; i < KA*WPAD*ALP; i += 256) {
    int k = i / (WPAD*ALP);
    int rem = i % (WPAD*ALP);
    int w = rem / ALP;
    int v = rem % ALP;
    float a = (w < V_ && v < V_) ? A[(k*V_ + v)*V_ + w] : 0.f;
    ((short*)Albf)[i] = f2bf(a);
  }
  // xt pad zero: v in [25,40)
  for (int i = tid; i < TT*C_*15; i += 256) {
    int t = i / (C_*15);
    int r = i % (C_*15);
    int c = r / 15;
    int v = V_ + (r % 15);
    xt[t][c][v] = 0;
  }
  // xt fill: coalesced float2 loads of x tile (128 c' x 50 floats)
  {
    const float* xb = x + (((size_t)n*C_)*T_ + t0)*V_;
    for (int p = tid; p < 3200; p += 256) {
      int c = (p*5243) >> 17;       // p/25
      int r = p - c*25;             // float2 index within the 50-float segment
      float2v xv = *(const float2v*)(xb + (size_t)c*(T_*V_) + 2*r);
      int j0 = 2*r;
      { int j = j0;   int t = (j >= V_); int v = j - t*V_; xt[t][c][v] = f2bf(xv[0]); }
      { int j = j0+1; int t = (j >= V_); int v = j - t*V_; xt[t][c][v] = f2bf(xv[1]); }
    }
  }
  __syncthreads();

  // ---- stage 1: X'[k*128+c'][t*32+w] = sum_v x[c',t,v]*A[k,v,w]
  #pragma unroll
  for (int iu = 0; iu < 3; ++iu) {
    int u  = wid*3 + iu;
    int mh = u / 6;
    int k  = (u >> 1) % 3;
    int t  = u & 1;
    short8 bf0 = *(const short8*)&Albf[k][l15][quad*8];
    short8 bf1 = *(const short8*)&Albf[k][16 + l15][quad*8];
    #pragma unroll
    for (int mi4 = 0; mi4 < 4; ++mi4) {
      int mi = mh*4 + mi4;
      int cp = mi*16 + l15;
      short8 af = *(const short8*)&xt[t][cp][quad*8];
      int c2 = k*C_ + mi*16 + quad*4;
      #pragma unroll
      for (int ni = 0; ni < 2; ++ni) {
        float4v acc = {0.f, 0.f, 0.f, 0.f};
        acc = __builtin_amdgcn_mfma_f32_16x16x32_bf16(af, ni ? bf1 : bf0, acc, 0, 0, 0);
        short4v sv;
        sv[0] = f2bf(acc[0]); sv[1] = f2bf(acc[1]);
        sv[2] = f2bf(acc[2]); sv[3] = f2bf(acc[3]);
        int pos = t*WPAD + ni*16 + l15;
        *(short4v*)&B2[pos][c2] = sv;
      }
    }
  }
  __syncthreads();

  // ---- stage 2: Z[c][pos] = sum_kd W2[c][kd] * X'[kd][pos]
  const int wm = wid >> 1;
  const int wn = wid & 1;
  float4v acc[4][2];
  #pragma unroll
  for (int mi = 0; mi < 4; ++mi)
    #pragma unroll
    for (int ni = 0; ni < 2; ++ni)
      acc[mi][ni] = (float4v){0.f, 0.f, 0.f, 0.f};

  #pragma unroll 4
  for (int ks = 0; ks < 12; ++ks) {
    short8 bfr0 = *(const short8*)&B2[wn*32 + l15][ks*32 + quad*8];
    short8 bfr1 = *(const short8*)&B2[wn*32 + 16 + l15][ks*32 + quad*8];
    #pragma unroll
    for (int mi = 0; mi < 4; ++mi) {
      int c = wm*64 + mi*16 + l15;
      short8 afr = *(const short8*)(W2 + (size_t)c*KDIM + ks*32 + quad*8);
      acc[mi][0] = __builtin_amdgcn_mfma_f32_16x16x32_bf16(afr, bfr0, acc[mi][0], 0, 0, 0);
      acc[mi][1] = __builtin_amdgcn_mfma_f32_16x16x32_bf16(afr, bfr1, acc[mi][1], 0, 0, 0);
    }
  }

  // ---- epilogue: +bias2, +x residual (LDS), relu; BN partials; z kept in acc
  float lsum[4][4], lsq[4][4];
  #pragma unroll
  for (int a1 = 0; a1 < 4; ++a1)
    #pragma unroll
    for (int a2 = 0; a2 < 4; ++a2) { lsum[a1][a2] = 0.f; lsq[a1][a2] = 0.f; }

  #pragma unroll
  for (int ni = 0; ni < 2; ++ni) {
    int pos = wn*32 + ni*16 + l15;
    int t = pos >> 5;
    int w = pos & 31;
    if (w < V_) {
      #pragma unroll
      for (int mi = 0; mi < 4; ++mi) {
        int cb = wm*64 + mi*16 + quad*4;
        #pragma unroll
        for (int r = 0; r < 4; ++r) {
          int cc = cb + r;
          float z = acc[mi][ni][r] + bias2[cc*32 + w];
          z += bf2f(xt[t][cc][w]);
          z = fmaxf(z, 0.f);
          acc[mi][ni][r] = z;
          lsum[mi][r] += z;
          lsq[mi][r]  += z*z;
        }
      }
    }
  }

  __syncthreads();   // all B2 reads complete; safe to alias as Zs
  float* Zs = (float*)&B2[0][0];   // [128][50] fp32 = 25.6KB

  #pragma unroll
  for (int ni = 0; ni < 2; ++ni) {
    int pos = wn*32 + ni*16 + l15;
    int t = pos >> 5;
    int w = pos & 31;
    if (w < V_) {
      #pragma unroll
      for (int mi = 0; mi < 4; ++mi) {
        int cb = wm*64 + mi*16 + quad*4;
        #pragma unroll
        for (int r = 0; r < 4; ++r) {
          Zs[(cb + r)*50 + t*V_ + w] = acc[mi][ni][r];
        }
      }
    }
  }
  __syncthreads();

  // coalesced cooperative store of Z tile to out
  {
    float* ob = out + (((size_t)n*C_)*T_ + t0)*V_;
    for (int p = tid; p < 3200; p += 256) {
      int c = (p*5243) >> 17;       // p/25
      int r = p - c*25;
      float2v zz = *(const float2v*)&Zs[c*50 + 2*r];
      *(float2v*)(ob + (size_t)c*(T_*V_) + 2*r) = zz;
    }
  }

  // BN partial sums
  int slot = nb & (NSLOT - 1);
  #pragma unroll
  for (int mi = 0; mi < 4; ++mi) {
    #pragma unroll
    for (int r = 0; r < 4; ++r) {
      float s = lsum[mi][r];
      float q = lsq[mi][r];
      #pragma unroll
      for (int m = 1; m <= 8; m <<= 1) {
        s += __shfl_xor(s, m, 64);
        q += __shfl_xor(q, m, 64);
      }
      if (l15 == 0) {
        int cc = wm*64 + mi*16 + quad*4 + r;
        atomicAdd(&ssum[slot*C_ + cc], s);
        atomicAdd(&ssq[slot*C_ + cc], q);
      }
    }
  }
}

// ---------------- K2: finalize BN scale/shift; copy A to output tail
__global__ __launch_bounds__(256) void k2_stats(const float* __restrict__ ssum,
    const float* __restrict__ ssq, const float* __restrict__ gamma,
    const float* __restrict__ beta, const float* __restrict__ A,
    float* __restrict__ sscale, float* __restrict__ sshift, float* __restrict__ outA)
{
  int id = blockIdx.x * 256 + threadIdx.x;
  if (id < C_) {
    float s = 0.f, q = 0.f;
    for (int sl = 0; sl < NSLOT; ++sl) { s += ssum[sl*C_ + id]; q += ssq[sl*C_ + id]; }
    const float cnt = 480000.f;   // N*T*V
    float mean = s / cnt;
    float var  = q / cnt - mean*mean;
    float inv  = rsqrtf(var + 1e-5f);
    float sc   = gamma[id] * inv;
    sscale[id] = sc;
    sshift[id] = beta[id] - mean * sc;
  } else if (id < C_ + KA*V_*V_) {
    int i = id - C_;
    outA[i] = A[i];
  }
}

// ---------------- K3: in-place BN apply; block = (n, 16-t chunk), aligned float4
__global__ __launch_bounds__(256) void k3_bn(float* __restrict__ out,
    const float* __restrict__ sscale, const float* __restrict__ sshift)
{
  __shared__ float s_sc[C_], s_sh[C_];
  int tid = threadIdx.x;
  if (tid < C_) s_sc[tid] = sscale[tid];
  else          s_sh[tid - C_] = sshift[tid - C_];
  __syncthreads();

  int n = blockIdx.x / 19;
  int chunk = blockIdx.x % 19;
  int t0c = chunk * 16;
  int tlen = (t0c + 16 <= T_) ? 16 : (T_ - t0c);   // 16 or 12
  int vlim = tlen * V_;                             // 400 or 300

  for (int f = tid; f < 12800; f += 256) {
    int c = (f*5243) >> 19;      // f/100
    int r = f - c*100;
    int idx0 = 4*r;
    if (idx0 >= vlim) continue;
    size_t off4 = ((size_t)n*C_*T_*V_ + (size_t)c*T_*V_ + (size_t)t0c*V_ + idx0) >> 2;
    float4v v = ((float4v*)out)[off4];
    float sc = s_sc[c], sh = s_sh[c];
    v[0] = v[0]*sc + sh; v[1] = v[1]*sc + sh;
    v[2] = v[2]*sc + sh; v[3] = v[3]*sc + sh;
    ((float4v*)out)[off4] = v;
  }
}

extern "C" void kernel_launch(void* const* d_in, const int* in_sizes, int n_in,
                              void* d_out, int out_size, void* d_ws, size_t ws_size,
                              hipStream_t stream)
{
  const float* x     = (const float*)d_in[0];
  const float* A     = (const float*)d_in[1];
  const float* W     = (const float*)d_in[2];
  const float* b     = (const float*)d_in[3];
  const float* gamma = (const float*)d_in[4];
  const float* beta  = (const float*)d_in[5];
  float* out = (float*)d_out;

  short* W2    = (short*)d_ws;                          // 98,304 B
  float* bias2 = (float*)((char*)d_ws + 98304);         // 16,384 B
  float* stats = (float*)((char*)d_ws + 114688);        // 65,536 B (sum|sq)
  float* ssum   = stats;
  float* ssq    = stats + NSLOT*C_;
  float* sscale = stats + 2*NSLOT*C_;
  float* sshift = sscale + C_;
  float* outA = out + (size_t)NTOT*C_*T_*V_;            // A tail at 61,440,000

  k0_prep <<<272,   256, 0, stream>>>(W, A, b, W2, bias2, stats);
  k1_main <<<9600,  256, 0, stream>>>(x, A, W2, bias2, ssum, ssq, out);
  k2_stats<<<8,     256, 0, stream>>>(ssum, ssq, gamma, beta, A, sscale, sshift, outA);
  k3_bn   <<<1216,  256, 0, stream>>>(out, sscale, sshift);
}